// Round 6
// baseline (151.990 us; speedup 1.0000x reference)
//
#include <hip/hip_runtime.h>
#include <hip/hip_bf16.h>

// Problem constants (B=2, T=2048, D=768, E=8, H=1536, K=2)
#define NTOK 4096
#define DDIM 768
#define EEXP 8
#define HDIM 1536
#define MBLK 128
#define MAXMB 72            // sum ceil(cnt_e/128) <= 64+7, +margin
#define CAP  (MAXMB * MBLK) // 9216
#define NENT (NTOK * 2)     // 8192 routed (token,k) entries
#define RTHREADS 1024
#define EPT (NENT / RTHREADS) // 8 entries per route thread

typedef float f32x4 __attribute__((ext_vector_type(4)));
typedef __bf16 bf16x8 __attribute__((ext_vector_type(8)));
typedef __bf16 bf16x4 __attribute__((ext_vector_type(4)));

// ---------------- workspace layout (bytes) ----------------
static const size_t XB_OFF   = 0;                       // bf16 x [NTOK][D]      6,291,456
static const size_t GT_OFF   = 6291456;                 // bf16 Gt [E][H][D]    18,874,368
static const size_t UT_OFF   = GT_OFF + 18874368;       // bf16 Ut [E][H][D]    18,874,368
static const size_t YB_OFF   = GT_OFF;                  // f32 ybuf [CAP][D]    28,311,552 (aliases Gt+Ut, dead after gateup)
static const size_t DT_OFF   = UT_OFF + 18874368;       // bf16 Dt [E][D][H]    18,874,368
static const size_t HB_OFF   = DT_OFF + 18874368;       // bf16 h  [CAP][H]     28,311,552
static const size_t TKI_OFF  = HB_OFF + 28311552;       // int  topk_idx [NENT]
static const size_t TKW_OFF  = TKI_OFF + NENT*4;        // f32  topk_w   [NENT]
static const size_t PT_OFF   = TKW_OFF + NENT*4;        // int  pair_token [CAP]
static const size_t SL_OFF   = PT_OFF + CAP*4;          // int  slot_of  [NENT]
static const size_t CTRL_OFF = SL_OFF + NENT*4;
static const size_t WS_NEEDED = CTRL_OFF + 1024;

#define GLOAD16(g, l) __builtin_amdgcn_global_load_lds( \
    (const __attribute__((address_space(1))) void*)(g),  \
    (__attribute__((address_space(3))) void*)(l), 16, 0, 0)

#define VMWAIT(N) asm volatile("s_waitcnt vmcnt(" #N ")" ::: "memory")
#define SFENCE()  __builtin_amdgcn_sched_barrier(0)
#define BAR()     __builtin_amdgcn_s_barrier()

// T2 swizzle: LDS tile rows are 64 bf16 (128 B). Fragment reads hit 16 rows at
// 128B stride = same bank (16-way). XOR the 16B-group index with (row&7):
// read addr = row*64 + (kb ^ ((row&7)<<3)); the global SOURCE column is
// pre-swizzled identically so gload_lds's linear write lands data there.

// ---------------- small kernels ----------------

__global__ __launch_bounds__(256) void convert_x_kernel(
    const float* __restrict__ x, __bf16* __restrict__ xb, int n4)
{
    int i = blockIdx.x * 256 + threadIdx.x;
    if (i < n4) {
        f32x4 v = reinterpret_cast<const f32x4*>(x)[i];
        bf16x4 o;
        o[0] = (__bf16)v[0]; o[1] = (__bf16)v[1];
        o[2] = (__bf16)v[2]; o[3] = (__bf16)v[3];
        reinterpret_cast<bf16x4*>(xb)[i] = o;
    }
}

// transpose last two dims + convert to bf16: src [z][R][C] f32 -> dst [z][C][R] bf16
// 64x64 tiles: bf16 stores are 128B contiguous per output row (was 64B at 32x32).
__global__ __launch_bounds__(256) void transpose64_kernel(
    const float* __restrict__ src, __bf16* __restrict__ dst, int R, int C)
{
    __shared__ float tile[64][65];   // 65-pad: both phases <=2-way banks (free)
    const float* s = src + (size_t)blockIdx.z * R * C;
    __bf16* d = dst + (size_t)blockIdx.z * R * C;
    int tx = threadIdx.x & 15, ty = threadIdx.x >> 4;   // 16 x 16
    int r0 = blockIdx.y * 64, c0 = blockIdx.x * 64;
#pragma unroll
    for (int j = 0; j < 4; j++) {
        int r = ty + j * 16;
        f32x4 v = *reinterpret_cast<const f32x4*>(&s[(size_t)(r0 + r) * C + c0 + tx * 4]);
        tile[r][tx*4+0] = v[0]; tile[r][tx*4+1] = v[1];
        tile[r][tx*4+2] = v[2]; tile[r][tx*4+3] = v[3];
    }
    __syncthreads();
#pragma unroll
    for (int j = 0; j < 4; j++) {
        int c = ty + j * 16;
        bf16x4 o;
#pragma unroll
        for (int i = 0; i < 4; i++) o[i] = (__bf16)tile[tx*4+i][c];
        *reinterpret_cast<bf16x4*>(&d[(size_t)(c0 + c) * R + r0 + tx*4]) = o;
    }
}

// one wave per token: 8 dots of length 768, softmax, top-2, normalized weights.
// NO atomics (8-address atomic contention serialized the whole kernel).
__global__ __launch_bounds__(256) void gating_kernel(
    const float* __restrict__ x, const float* __restrict__ gw,
    int* __restrict__ topk_idx, float* __restrict__ topk_w)
{
    int lane = threadIdx.x & 63;
    int t = blockIdx.x * 4 + (threadIdx.x >> 6);
    const float* xr = x + (size_t)t * DDIM;
    float acc[EEXP];
#pragma unroll
    for (int e = 0; e < EEXP; e++) acc[e] = 0.0f;
    for (int i = 0; i < DDIM / 64; i++) {
        int d = lane + i * 64;
        float xv = xr[d];
#pragma unroll
        for (int e = 0; e < EEXP; e++) acc[e] += xv * gw[e * DDIM + d];
    }
#pragma unroll
    for (int e = 0; e < EEXP; e++) {
        for (int off = 32; off; off >>= 1) acc[e] += __shfl_xor(acc[e], off);
    }
    if (lane == 0) {
        float m = acc[0];
#pragma unroll
        for (int e = 1; e < EEXP; e++) m = fmaxf(m, acc[e]);
        float p[EEXP], sum = 0.0f;
#pragma unroll
        for (int e = 0; e < EEXP; e++) { p[e] = expf(acc[e] - m); sum += p[e]; }
        int i0 = 0; float b0 = acc[0];
#pragma unroll
        for (int e = 1; e < EEXP; e++) if (acc[e] > b0) { b0 = acc[e]; i0 = e; }
        int i1 = -1; float b1 = -3.4e38f;
#pragma unroll
        for (int e = 0; e < EEXP; e++) if (e != i0 && acc[e] > b1) { b1 = acc[e]; i1 = e; }
        float pr0 = p[i0] / sum, pr1 = p[i1] / sum;
        float den = pr0 + pr1 + 1e-8f;
        topk_idx[2*t]   = i0; topk_w[2*t]   = pr0 / den;
        topk_idx[2*t+1] = i1; topk_w[2*t+1] = pr1 / den;
    }
}

// single-block deterministic routing: zero-init pads + counts + 128-aligned
// offsets + mblock table + slot assignment via shfl/LDS prefix scans. No atomics.
__global__ __launch_bounds__(RTHREADS) void route_kernel(
    const int* __restrict__ topk_idx, int* __restrict__ ctrl,
    int* __restrict__ pair_token, int* __restrict__ slot_of)
{
    __shared__ int wt[EEXP][16];    // per-wave totals
    __shared__ int wpre[EEXP][16];  // exclusive prefix of wave totals
    __shared__ int base[EEXP];      // 128-aligned expert base slot

    int tid = threadIdx.x;
    int lane = tid & 63, wv = tid >> 6;

    // zero pad slots (poisoned ws would otherwise feed garbage token indices)
    for (int i = tid; i < CAP; i += RTHREADS) pair_token[i] = 0;

    int e_of[EPT];
    int c[EEXP];
#pragma unroll
    for (int e = 0; e < EEXP; e++) c[e] = 0;
#pragma unroll
    for (int j = 0; j < EPT; j++) {
        int e = topk_idx[tid * EPT + j];
        e_of[j] = e;
        c[e]++;
    }

    // per-expert exclusive prefix within wave + wave total
    int pre[EEXP];
#pragma unroll
    for (int e = 0; e < EEXP; e++) {
        int v = c[e];
        for (int d = 1; d < 64; d <<= 1) {
            int u = __shfl_up(v, d);
            if (lane >= d) v += u;
        }
        pre[e] = v - c[e];
        if (lane == 63) wt[e][wv] = v;
    }
    __syncthreads();

    if (tid == 0) {
        int off = 0, gmb = 0;
        for (int e = 0; e < EEXP; e++) {
            int run = 0;
            for (int w = 0; w < 16; w++) { wpre[e][w] = run; run += wt[e][w]; }
            base[e] = off;
            int nmb = (run + MBLK - 1) >> 7;
            for (int i = 0; i < nmb; i++) ctrl[32 + gmb++] = e;
            off += nmb << 7;
        }
        ctrl[24] = gmb;
    }
    __syncthreads();

    int run[EEXP];
#pragma unroll
    for (int e = 0; e < EEXP; e++) run[e] = base[e] + wpre[e][wv] + pre[e];
#pragma unroll
    for (int j = 0; j < EPT; j++) {
        int ent = tid * EPT + j;
        int e = e_of[j];
        int slot = run[e]++;
        pair_token[slot] = ent >> 1;
        slot_of[ent] = slot;
    }
}

// ------- gate/up fused GEMM: 3-buf counted-vmcnt pipeline + T2 swizzle -------
// Tile: 128 pairs x 128 h-cols, BK=64, K=768 (12 steps). 512 thr = 8 waves (2x4),
// wave tile 64x32. LDS: 3 x 48KB = 144KB (1 block/CU). Prefetch distance 2;
// vmcnt NEVER drained to 0 in the main loop (T4).
__global__ __launch_bounds__(512, 2) void gateup_kernel(
    const __bf16* __restrict__ xb, const __bf16* __restrict__ Gt,
    const __bf16* __restrict__ Ut, const int* __restrict__ ctrl,
    const int* __restrict__ pair_token, __bf16* __restrict__ hbuf)
{
    // flattened grid, y-fastest; bijective XCD chunk swizzle (864 % 8 == 0)
    int bid = blockIdx.x;
    int swz = (bid & 7) * (MAXMB * 12 / 8) + (bid >> 3);
    int mb = swz / 12, y = swz - mb * 12;
    if (mb >= ctrl[24]) return;
    int e = ctrl[32 + mb];
    int hbase = y * 128;
    const __bf16* G = Gt + (size_t)e * HDIM * DDIM;   // [H][D]
    const __bf16* U = Ut + (size_t)e * HDIM * DDIM;

    __shared__ __bf16 lds[3 * 24576];   // 144 KB: [buf][A|Bg|Bu][128*64]

    int tid = threadIdx.x;
    int lane = tid & 63, w = tid >> 6;
    int wr = w >> 2, wc = w & 3;

    // staging: each GLOAD16 set = 512 thr x 16B = one 64-row x 64-col chunk.
    // source col pre-swizzled so linear LDS write realizes the XOR layout.
    int lr = tid >> 3;                                 // row in chunk, 0..63
    int lc = ((tid & 7) ^ (lr & 7)) << 3;              // swizzled col elem
    int tok0 = pair_token[mb * MBLK + lr];
    int tok1 = pair_token[mb * MBLK + 64 + lr];
    const __bf16* gA0 = xb + (size_t)tok0 * DDIM + lc;
    const __bf16* gA1 = xb + (size_t)tok1 * DDIM + lc;
    const __bf16* gG0 = G + (size_t)(hbase + lr) * DDIM + lc;
    const __bf16* gU0 = U + (size_t)(hbase + lr) * DDIM + lc;
    const size_t bstep = (size_t)64 * DDIM;            // +64 B-rows

    f32x4 accg[4][2], accu[4][2];
#pragma unroll
    for (int m = 0; m < 4; m++)
#pragma unroll
        for (int n = 0; n < 2; n++) { accg[m][n] = (f32x4)0.0f; accu[m][n] = (f32x4)0.0f; }

    auto stage = [&](int buf, int kk) {
        __bf16* d = &lds[buf * 24576];
        GLOAD16(gA0 + kk, d + tid * 8);
        GLOAD16(gA1 + kk, d + 4096 + tid * 8);
        GLOAD16(gG0 + kk, d + 8192 + tid * 8);
        GLOAD16(gG0 + kk + bstep, d + 12288 + tid * 8);
        GLOAD16(gU0 + kk, d + 16384 + tid * 8);
        GLOAD16(gU0 + kk + bstep, d + 20480 + tid * 8);
    };

    // prologue: 12 loads in flight (tiles 0,1)
    stage(0, 0);
    stage(1, 64);
    SFENCE();

#pragma unroll
    for (int t = 0; t < 12; ++t) {
        if (t < 10) stage((t + 2) % 3, (t + 2) * 64);   // +6 -> 18 in flight
        SFENCE();
        // retire ONLY tile t's 6 loads; t+1/t+2 stay in flight across barriers
        if (t < 10) { VMWAIT(12); } else if (t == 10) { VMWAIT(6); } else { VMWAIT(0); }
        SFENCE();
        BAR();           // all waves' tile-t staging now visible
        SFENCE();

        const __bf16* A  = &lds[(t % 3) * 24576];
        const __bf16* Bg = A + 8192;
        const __bf16* Bu = A + 16384;
#pragma unroll
        for (int ks = 0; ks < 2; ks++) {
            int kb = ks * 32 + (lane >> 4) * 8;
            bf16x8 af[4];
#pragma unroll
            for (int m = 0; m < 4; m++) {
                int row = wr * 64 + m * 16 + (lane & 15);
                af[m] = *reinterpret_cast<const bf16x8*>(
                    &A[row * 64 + (kb ^ ((row & 7) << 3))]);
            }
            __builtin_amdgcn_s_setprio(1);
#pragma unroll
            for (int n = 0; n < 2; n++) {
                int col = wc * 32 + n * 16 + (lane & 15);
                int ba = col * 64 + (kb ^ ((col & 7) << 3));
                bf16x8 bg = *reinterpret_cast<const bf16x8*>(&Bg[ba]);
                bf16x8 bu = *reinterpret_cast<const bf16x8*>(&Bu[ba]);
#pragma unroll
                for (int m = 0; m < 4; m++) {
                    accg[m][n] = __builtin_amdgcn_mfma_f32_16x16x32_bf16(af[m], bg, accg[m][n], 0, 0, 0);
                    accu[m][n] = __builtin_amdgcn_mfma_f32_16x16x32_bf16(af[m], bu, accu[m][n], 0, 0, 0);
                }
            }
            __builtin_amdgcn_s_setprio(0);
        }
        SFENCE();
        BAR();           // tile-t reads done -> buf[(t+2)%3] safe to overwrite next iter
        SFENCE();
    }

    size_t slotbase = (size_t)mb * MBLK;
#pragma unroll
    for (int m = 0; m < 4; m++)
#pragma unroll
        for (int n = 0; n < 2; n++)
#pragma unroll
            for (int r = 0; r < 4; r++) {
                int row = wr * 64 + m * 16 + (lane >> 4) * 4 + r;
                int col = hbase + wc * 32 + n * 16 + (lane & 15);
                float a = accg[m][n][r], u = accu[m][n][r];
                float hv = (a / (1.0f + expf(-a))) * u;
                hbuf[(slotbase + row) * HDIM + col] = (__bf16)hv;
            }
}

// ------- down GEMM: 2-buf counted-vmcnt pipeline + T2 swizzle -------
// Tile: 128 pairs x 128 d-cols, BK=64, K=1536 (24 steps). 512 thr, 8 waves (2x4).
// LDS: 2 x 32KB = 64 KB (2 blocks/CU). Prefetch distance 1, steady vmcnt(4).
__global__ __launch_bounds__(512, 4) void down_kernel(
    const __bf16* __restrict__ hbuf, const __bf16* __restrict__ Dt,
    const int* __restrict__ ctrl, float* __restrict__ ybuf)
{
    int bid = blockIdx.x;
    int swz = (bid & 7) * (MAXMB * 6 / 8) + (bid >> 3);   // 432 % 8 == 0
    int mb = swz / 6, y = swz - mb * 6;
    if (mb >= ctrl[24]) return;
    int e = ctrl[32 + mb];
    int dbase = y * 128;
    const __bf16* Dn = Dt + (size_t)e * DDIM * HDIM;   // [D][H]

    __shared__ __bf16 lds[2 * 16384];   // 64 KB: [buf][A|B][128*64]

    int tid = threadIdx.x;
    int lane = tid & 63, w = tid >> 6;
    int wr = w >> 2, wc = w & 3;

    int lr = tid >> 3;
    int lc = ((tid & 7) ^ (lr & 7)) << 3;
    const __bf16* gA0 = hbuf + (size_t)(mb * MBLK + lr) * HDIM + lc;
    const __bf16* gB0 = Dn + (size_t)(dbase + lr) * HDIM + lc;
    const size_t astep = (size_t)64 * HDIM;

    f32x4 acc[4][2];
#pragma unroll
    for (int m = 0; m < 4; m++)
#pragma unroll
        for (int n = 0; n < 2; n++) acc[m][n] = (f32x4)0.0f;

    auto stage = [&](int buf, int kk) {
        __bf16* d = &lds[buf * 16384];
        GLOAD16(gA0 + kk, d + tid * 8);
        GLOAD16(gA0 + kk + astep, d + 4096 + tid * 8);
        GLOAD16(gB0 + kk, d + 8192 + tid * 8);
        GLOAD16(gB0 + kk + astep, d + 12288 + tid * 8);
    };

    stage(0, 0);          // 4 in flight
    SFENCE();

#pragma unroll
    for (int t = 0; t < 24; ++t) {
        if (t < 23) stage((t + 1) & 1, (t + 1) * 64);   // +4 -> 8 in flight
        SFENCE();
        if (t < 23) { VMWAIT(4); } else { VMWAIT(0); }  // retire only tile t's 4
        SFENCE();
        BAR();
        SFENCE();

        const __bf16* A = &lds[(t & 1) * 16384];
        const __bf16* B = A + 8192;
#pragma unroll
        for (int ks = 0; ks < 2; ks++) {
            int kb = ks * 32 + (lane >> 4) * 8;
            bf16x8 af[4];
#pragma unroll
            for (int m = 0; m < 4; m++) {
                int row = wr * 64 + m * 16 + (lane & 15);
                af[m] = *reinterpret_cast<const bf16x8*>(
                    &A[row * 64 + (kb ^ ((row & 7) << 3))]);
            }
            __builtin_amdgcn_s_setprio(1);
#pragma unroll
            for (int n = 0; n < 2; n++) {
                int col = wc * 32 + n * 16 + (lane & 15);
                bf16x8 bd = *reinterpret_cast<const bf16x8*>(
                    &B[col * 64 + (kb ^ ((col & 7) << 3))]);
#pragma unroll
                for (int m = 0; m < 4; m++)
                    acc[m][n] = __builtin_amdgcn_mfma_f32_16x16x32_bf16(af[m], bd, acc[m][n], 0, 0, 0);
            }
            __builtin_amdgcn_s_setprio(0);
        }
        SFENCE();
        BAR();            // tile-t reads done -> buf[(t+1)&1] safe to overwrite
        SFENCE();
    }

#pragma unroll
    for (int m = 0; m < 4; m++)
#pragma unroll
        for (int n = 0; n < 2; n++)
#pragma unroll
            for (int r = 0; r < 4; r++) {
                int row = wr * 64 + m * 16 + (lane >> 4) * 4 + r;
                int col = dbase + wc * 32 + n * 16 + (lane & 15);
                ybuf[(size_t)(mb * MBLK + row) * DDIM + col] = acc[m][n][r];
            }
}

// combine: out[t] = w0*y[s0] + w1*y[s1]; fully overwrites d_out.
__global__ __launch_bounds__(192) void combine_kernel(
    const float* __restrict__ ybuf, const int* __restrict__ slot_of,
    const float* __restrict__ topk_w, float* __restrict__ out)
{
    int t = blockIdx.x;
    int q = threadIdx.x;
    int s0 = slot_of[2*t], s1 = slot_of[2*t+1];
    float w0 = topk_w[2*t], w1 = topk_w[2*t+1];
    f32x4 y0 = reinterpret_cast<const f32x4*>(ybuf + (size_t)s0 * DDIM)[q];
    f32x4 y1 = reinterpret_cast<const f32x4*>(ybuf + (size_t)s1 * DDIM)[q];
    f32x4 o;
#pragma unroll
    for (int r = 0; r < 4; r++) o[r] = w0 * y0[r] + w1 * y1[r];
    reinterpret_cast<f32x4*>(out + (size_t)t * DDIM)[q] = o;
}

// ---------------- launch ----------------
extern "C" void kernel_launch(void* const* d_in, const int* in_sizes, int n_in,
                              void* d_out, int out_size, void* d_ws, size_t ws_size,
                              hipStream_t stream)
{
    if (ws_size < WS_NEEDED) return;

    const float* x      = (const float*)d_in[0];
    const float* gate_w = (const float*)d_in[1];
    const float* gbank  = (const float*)d_in[2];
    const float* ubank  = (const float*)d_in[3];
    const float* dbank  = (const float*)d_in[4];
    float* out = (float*)d_out;

    char* ws = (char*)d_ws;
    __bf16* xb   = (__bf16*)(ws + XB_OFF);
    __bf16* Gt   = (__bf16*)(ws + GT_OFF);
    __bf16* Ut   = (__bf16*)(ws + UT_OFF);
    float*  ybuf = (float*)(ws + YB_OFF);
    __bf16* Dt   = (__bf16*)(ws + DT_OFF);
    __bf16* hbuf = (__bf16*)(ws + HB_OFF);
    int*    tki  = (int*)(ws + TKI_OFF);
    float*  tkw  = (float*)(ws + TKW_OFF);
    int*    pt   = (int*)(ws + PT_OFF);
    int*    slot = (int*)(ws + SL_OFF);
    int*    ctrl = (int*)(ws + CTRL_OFF);

    convert_x_kernel<<<(NTOK * DDIM / 4 + 255) / 256, 256, 0, stream>>>(x, xb, NTOK * DDIM / 4);

    // gate_bank [E][768][1536] -> Gt [E][1536][768]
    transpose64_kernel<<<dim3(HDIM/64, DDIM/64, EEXP), 256, 0, stream>>>(gbank, Gt, DDIM, HDIM);
    transpose64_kernel<<<dim3(HDIM/64, DDIM/64, EEXP), 256, 0, stream>>>(ubank, Ut, DDIM, HDIM);
    // down_bank [E][1536][768] -> Dt [E][768][1536]
    transpose64_kernel<<<dim3(DDIM/64, HDIM/64, EEXP), 256, 0, stream>>>(dbank, Dt, HDIM, DDIM);

    gating_kernel<<<NTOK / 4, 256, 0, stream>>>(x, gate_w, tki, tkw);
    route_kernel<<<1, RTHREADS, 0, stream>>>(tki, ctrl, pt, slot);

    gateup_kernel<<<MAXMB * (HDIM / 128), 512, 0, stream>>>(xb, Gt, Ut, ctrl, pt, hbuf);
    down_kernel<<<MAXMB * (DDIM / 128), 512, 0, stream>>>(hbuf, Dt, ctrl, ybuf);
    combine_kernel<<<NTOK, 192, 0, stream>>>(ybuf, slot, tkw, out);
}

// Round 7
// 151.758 us; speedup vs baseline: 1.0015x; 1.0015x over previous
//
#include <hip/hip_runtime.h>
#include <hip/hip_bf16.h>

// Problem constants (B=2, T=2048, D=768, E=8, H=1536, K=2)
#define NTOK 4096
#define DDIM 768
#define EEXP 8
#define HDIM 1536
#define MBLK 128
#define MAXMB 72            // sum ceil(cnt_e/128) <= 64+7, +margin
#define CAP  (MAXMB * MBLK) // 9216
#define NENT (NTOK * 2)     // 8192 routed (token,k) entries
#define RTHREADS 1024
#define EPT (NENT / RTHREADS) // 8 entries per route thread

typedef float f32x4 __attribute__((ext_vector_type(4)));
typedef __bf16 bf16x8 __attribute__((ext_vector_type(8)));
typedef __bf16 bf16x4 __attribute__((ext_vector_type(4)));

// ---------------- workspace layout (bytes) ----------------
static const size_t XB_OFF   = 0;                       // bf16 x [NTOK][D]      6,291,456
static const size_t GT_OFF   = 6291456;                 // bf16 Gt [E][H][D]    18,874,368
static const size_t UT_OFF   = GT_OFF + 18874368;       // bf16 Ut [E][H][D]    18,874,368
static const size_t YB_OFF   = GT_OFF;                  // f32 ybuf [CAP][D]    28,311,552 (aliases Gt+Ut, dead after gateup)
static const size_t DT_OFF   = UT_OFF + 18874368;       // bf16 Dt [E][D][H]    18,874,368
static const size_t HB_OFF   = DT_OFF + 18874368;       // bf16 h  [CAP][H]     28,311,552
static const size_t TKI_OFF  = HB_OFF + 28311552;       // int  topk_idx [NENT]
static const size_t TKW_OFF  = TKI_OFF + NENT*4;        // f32  topk_w   [NENT]
static const size_t PT_OFF   = TKW_OFF + NENT*4;        // int  pair_token [CAP]
static const size_t SL_OFF   = PT_OFF + CAP*4;          // int  slot_of  [NENT]
static const size_t CTRL_OFF = SL_OFF + NENT*4;
static const size_t WS_NEEDED = CTRL_OFF + 1024;

#define GLOAD16(g, l) __builtin_amdgcn_global_load_lds( \
    (const __attribute__((address_space(1))) void*)(g),  \
    (__attribute__((address_space(3))) void*)(l), 16, 0, 0)

#define VMWAIT(N) asm volatile("s_waitcnt vmcnt(" #N ")" ::: "memory")
#define LGKM0()   asm volatile("s_waitcnt lgkmcnt(0)" ::: "memory")
#define SFENCE()  __builtin_amdgcn_sched_barrier(0)
#define BAR()     __builtin_amdgcn_s_barrier()

#define MFMA_BF16 __builtin_amdgcn_mfma_f32_16x16x32_bf16

// T2 swizzle: LDS tile rows are 64 bf16 (128 B). Fragment reads hit 16 rows at
// 128B stride = same bank (16-way). XOR the 16B-group index with (row&7):
// read addr = row*64 + (kb ^ ((row&7)<<3)); the global SOURCE column is
// pre-swizzled identically so gload_lds's linear write lands data there.

// ---------------- small kernels ----------------

__global__ __launch_bounds__(256) void convert_x_kernel(
    const float* __restrict__ x, __bf16* __restrict__ xb, int n4)
{
    int i = blockIdx.x * 256 + threadIdx.x;
    if (i < n4) {
        f32x4 v = reinterpret_cast<const f32x4*>(x)[i];
        bf16x4 o;
        o[0] = (__bf16)v[0]; o[1] = (__bf16)v[1];
        o[2] = (__bf16)v[2]; o[3] = (__bf16)v[3];
        reinterpret_cast<bf16x4*>(xb)[i] = o;
    }
}

// transpose last two dims + convert to bf16: src [z][R][C] f32 -> dst [z][C][R] bf16
__global__ __launch_bounds__(256) void transpose64_kernel(
    const float* __restrict__ src, __bf16* __restrict__ dst, int R, int C)
{
    __shared__ float tile[64][65];   // 65-pad: both phases <=2-way banks (free)
    const float* s = src + (size_t)blockIdx.z * R * C;
    __bf16* d = dst + (size_t)blockIdx.z * R * C;
    int tx = threadIdx.x & 15, ty = threadIdx.x >> 4;   // 16 x 16
    int r0 = blockIdx.y * 64, c0 = blockIdx.x * 64;
#pragma unroll
    for (int j = 0; j < 4; j++) {
        int r = ty + j * 16;
        f32x4 v = *reinterpret_cast<const f32x4*>(&s[(size_t)(r0 + r) * C + c0 + tx * 4]);
        tile[r][tx*4+0] = v[0]; tile[r][tx*4+1] = v[1];
        tile[r][tx*4+2] = v[2]; tile[r][tx*4+3] = v[3];
    }
    __syncthreads();
#pragma unroll
    for (int j = 0; j < 4; j++) {
        int c = ty + j * 16;
        bf16x4 o;
#pragma unroll
        for (int i = 0; i < 4; i++) o[i] = (__bf16)tile[tx*4+i][c];
        *reinterpret_cast<bf16x4*>(&d[(size_t)(c0 + c) * R + r0 + tx*4]) = o;
    }
}

// one wave per token: 8 dots of length 768, softmax, top-2, normalized weights.
// NO atomics (8-address atomic contention serialized the whole kernel).
__global__ __launch_bounds__(256) void gating_kernel(
    const float* __restrict__ x, const float* __restrict__ gw,
    int* __restrict__ topk_idx, float* __restrict__ topk_w)
{
    int lane = threadIdx.x & 63;
    int t = blockIdx.x * 4 + (threadIdx.x >> 6);
    const float* xr = x + (size_t)t * DDIM;
    float acc[EEXP];
#pragma unroll
    for (int e = 0; e < EEXP; e++) acc[e] = 0.0f;
    for (int i = 0; i < DDIM / 64; i++) {
        int d = lane + i * 64;
        float xv = xr[d];
#pragma unroll
        for (int e = 0; e < EEXP; e++) acc[e] += xv * gw[e * DDIM + d];
    }
#pragma unroll
    for (int e = 0; e < EEXP; e++) {
        for (int off = 32; off; off >>= 1) acc[e] += __shfl_xor(acc[e], off);
    }
    if (lane == 0) {
        float m = acc[0];
#pragma unroll
        for (int e = 1; e < EEXP; e++) m = fmaxf(m, acc[e]);
        float p[EEXP], sum = 0.0f;
#pragma unroll
        for (int e = 0; e < EEXP; e++) { p[e] = expf(acc[e] - m); sum += p[e]; }
        int i0 = 0; float b0 = acc[0];
#pragma unroll
        for (int e = 1; e < EEXP; e++) if (acc[e] > b0) { b0 = acc[e]; i0 = e; }
        int i1 = -1; float b1 = -3.4e38f;
#pragma unroll
        for (int e = 0; e < EEXP; e++) if (e != i0 && acc[e] > b1) { b1 = acc[e]; i1 = e; }
        float pr0 = p[i0] / sum, pr1 = p[i1] / sum;
        float den = pr0 + pr1 + 1e-8f;
        topk_idx[2*t]   = i0; topk_w[2*t]   = pr0 / den;
        topk_idx[2*t+1] = i1; topk_w[2*t+1] = pr1 / den;
    }
}

// single-block deterministic routing: zero-init pads + counts + 128-aligned
// offsets + mblock table + slot assignment via shfl/LDS prefix scans. No atomics.
__global__ __launch_bounds__(RTHREADS) void route_kernel(
    const int* __restrict__ topk_idx, int* __restrict__ ctrl,
    int* __restrict__ pair_token, int* __restrict__ slot_of)
{
    __shared__ int wt[EEXP][16];    // per-wave totals
    __shared__ int wpre[EEXP][16];  // exclusive prefix of wave totals
    __shared__ int base[EEXP];      // 128-aligned expert base slot

    int tid = threadIdx.x;
    int lane = tid & 63, wv = tid >> 6;

    // zero pad slots (poisoned ws would otherwise feed garbage token indices)
    for (int i = tid; i < CAP; i += RTHREADS) pair_token[i] = 0;

    int e_of[EPT];
    int c[EEXP];
#pragma unroll
    for (int e = 0; e < EEXP; e++) c[e] = 0;
#pragma unroll
    for (int j = 0; j < EPT; j++) {
        int e = topk_idx[tid * EPT + j];
        e_of[j] = e;
        c[e]++;
    }

    // per-expert exclusive prefix within wave + wave total
    int pre[EEXP];
#pragma unroll
    for (int e = 0; e < EEXP; e++) {
        int v = c[e];
        for (int d = 1; d < 64; d <<= 1) {
            int u = __shfl_up(v, d);
            if (lane >= d) v += u;
        }
        pre[e] = v - c[e];
        if (lane == 63) wt[e][wv] = v;
    }
    __syncthreads();

    if (tid == 0) {
        int off = 0, gmb = 0;
        for (int e = 0; e < EEXP; e++) {
            int run = 0;
            for (int w = 0; w < 16; w++) { wpre[e][w] = run; run += wt[e][w]; }
            base[e] = off;
            int nmb = (run + MBLK - 1) >> 7;
            for (int i = 0; i < nmb; i++) ctrl[32 + gmb++] = e;
            off += nmb << 7;
        }
        ctrl[24] = gmb;
    }
    __syncthreads();

    int run[EEXP];
#pragma unroll
    for (int e = 0; e < EEXP; e++) run[e] = base[e] + wpre[e][wv] + pre[e];
#pragma unroll
    for (int j = 0; j < EPT; j++) {
        int ent = tid * EPT + j;
        int e = e_of[j];
        int slot = run[e]++;
        pair_token[slot] = ent >> 1;
        slot_of[ent] = slot;
    }
}

// ------- gate/up fused GEMM: phase-split pipeline (T3+T4+T5) + T2 swizzle -------
// Tile: 128 pairs x 128 h-cols, BK=64, K=768 (12 steps). 512 thr = 8 waves (2x4),
// wave tile 64x32. LDS: 3 x 48KB = 144 KB. Per K-step: 2 phases of
// {8 ds_read || 3 gload -> bar -> lgkm0 -> 16 MFMA (setprio) -> bar}.
// vmcnt counted once per step (steady 6), never drained in main loop.
__global__ __launch_bounds__(512, 2) void gateup_kernel(
    const __bf16* __restrict__ xb, const __bf16* __restrict__ Gt,
    const __bf16* __restrict__ Ut, const int* __restrict__ ctrl,
    const int* __restrict__ pair_token, __bf16* __restrict__ hbuf)
{
    // flattened grid, y-fastest; bijective XCD chunk swizzle (864 % 8 == 0)
    int bid = blockIdx.x;
    int swz = (bid & 7) * (MAXMB * 12 / 8) + (bid >> 3);
    int mb = swz / 12, y = swz - mb * 12;
    if (mb >= ctrl[24]) return;
    int e = ctrl[32 + mb];
    int hbase = y * 128;
    const __bf16* G = Gt + (size_t)e * HDIM * DDIM;   // [H][D]
    const __bf16* U = Ut + (size_t)e * HDIM * DDIM;

    __shared__ __bf16 lds[3 * 24576];   // 144 KB: [buf][A|Bg|Bu][128*64]

    int tid = threadIdx.x;
    int lane = tid & 63, w = tid >> 6;
    int wr = w >> 2, wc = w & 3;

    // staging: each GLOAD16 = 512 thr x 16B = one 64-row x 64-col chunk.
    // source col pre-swizzled so linear LDS write realizes the XOR layout.
    int lr = tid >> 3;                                 // row in chunk, 0..63
    int lc = ((tid & 7) ^ (lr & 7)) << 3;              // swizzled col elem
    int tok0 = pair_token[mb * MBLK + lr];
    int tok1 = pair_token[mb * MBLK + 64 + lr];
    const __bf16* gA0 = xb + (size_t)tok0 * DDIM + lc;
    const __bf16* gA1 = xb + (size_t)tok1 * DDIM + lc;
    const __bf16* gG0 = G + (size_t)(hbase + lr) * DDIM + lc;
    const __bf16* gU0 = U + (size_t)(hbase + lr) * DDIM + lc;
    const size_t bstep = (size_t)64 * DDIM;            // +64 B-rows

    f32x4 accg[4][2], accu[4][2];
#pragma unroll
    for (int m = 0; m < 4; m++)
#pragma unroll
        for (int n = 0; n < 2; n++) { accg[m][n] = (f32x4)0.0f; accu[m][n] = (f32x4)0.0f; }

    auto stageA = [&](int buf, int kk) {   // per-wave 3 gloads: A0, A1, G0
        __bf16* d = &lds[buf * 24576];
        GLOAD16(gA0 + kk, d + tid * 8);
        GLOAD16(gA1 + kk, d + 4096 + tid * 8);
        GLOAD16(gG0 + kk, d + 8192 + tid * 8);
    };
    auto stageB = [&](int buf, int kk) {   // per-wave 3 gloads: G1, U0, U1
        __bf16* d = &lds[buf * 24576];
        GLOAD16(gG0 + kk + bstep, d + 12288 + tid * 8);
        GLOAD16(gU0 + kk, d + 16384 + tid * 8);
        GLOAD16(gU0 + kk + bstep, d + 20480 + tid * 8);
    };
    auto rdfrags = [&](const __bf16* A, const __bf16* Bg, const __bf16* Bu,
                       int ks, bf16x8* af, bf16x8* bg, bf16x8* bu) {
        int kb = ks * 32 + (lane >> 4) * 8;
#pragma unroll
        for (int m = 0; m < 4; m++) {
            int row = wr * 64 + m * 16 + (lane & 15);
            af[m] = *reinterpret_cast<const bf16x8*>(&A[row * 64 + (kb ^ ((row & 7) << 3))]);
        }
#pragma unroll
        for (int n = 0; n < 2; n++) {
            int col = wc * 32 + n * 16 + (lane & 15);
            int ba = col * 64 + (kb ^ ((col & 7) << 3));
            bg[n] = *reinterpret_cast<const bf16x8*>(&Bg[ba]);
            bu[n] = *reinterpret_cast<const bf16x8*>(&Bu[ba]);
        }
    };
    auto domfma = [&](bf16x8* af, bf16x8* bg, bf16x8* bu) {
        __builtin_amdgcn_s_setprio(1);
#pragma unroll
        for (int n = 0; n < 2; n++)
#pragma unroll
            for (int m = 0; m < 4; m++) {
                accg[m][n] = MFMA_BF16(af[m], bg[n], accg[m][n], 0, 0, 0);
                accu[m][n] = MFMA_BF16(af[m], bu[n], accu[m][n], 0, 0, 0);
            }
        __builtin_amdgcn_s_setprio(0);
    };

    // prologue: tiles 0,1 staged -> 12 outstanding/wave; retire tile0's 6
    stageA(0, 0);   stageB(0, 0);
    stageA(1, 64);  stageB(1, 64);
    SFENCE();
    VMWAIT(6);
    SFENCE();
    BAR();
    SFENCE();

#pragma unroll
    for (int t = 0; t < 12; ++t) {
        const __bf16* A  = &lds[(t % 3) * 24576];
        const __bf16* Bg = A + 8192;
        const __bf16* Bu = A + 16384;
        int kk2 = (t + 2) * 64;
        bf16x8 af[4], bg[2], bu[2];

        // ---- phase 0 (ks=0): reads || stage half, then MFMA
        rdfrags(A, Bg, Bu, 0, af, bg, bu);
        if (t < 10) stageA((t + 2) % 3, kk2);
        SFENCE();
        BAR();
        LGKM0();
        SFENCE();
        domfma(af, bg, bu);
        SFENCE();
        BAR();
        SFENCE();

        // ---- phase 1 (ks=1)
        rdfrags(A, Bg, Bu, 1, af, bg, bu);
        if (t < 10) stageB((t + 2) % 3, kk2);
        SFENCE();
        // retire ONLY tile (t+1)'s 6 loads; (t+2)'s stay in flight across barrier
        if (t < 10) { VMWAIT(6); } else if (t == 10) { VMWAIT(0); }
        SFENCE();
        BAR();
        LGKM0();
        SFENCE();
        domfma(af, bg, bu);
        SFENCE();
        BAR();
        SFENCE();
    }

    size_t slotbase = (size_t)mb * MBLK;
#pragma unroll
    for (int m = 0; m < 4; m++)
#pragma unroll
        for (int n = 0; n < 2; n++)
#pragma unroll
            for (int r = 0; r < 4; r++) {
                int row = wr * 64 + m * 16 + (lane >> 4) * 4 + r;
                int col = hbase + wc * 32 + n * 16 + (lane & 15);
                float a = accg[m][n][r], u = accu[m][n][r];
                float hv = (a / (1.0f + expf(-a))) * u;
                hbuf[(slotbase + row) * HDIM + col] = (__bf16)hv;
            }
}

// ------- down GEMM: phase-split pipeline + T2 swizzle -------
// Tile: 128 pairs x 128 d-cols, BK=64, K=1536 (24 steps). 512 thr, 8 waves.
// LDS: 3 x 32KB = 96 KB. Per K-step: 2 phases of {6 ds_read || 2 gload ->
// bar -> lgkm0 -> 8 MFMA -> bar}; steady vmcnt(4).
__global__ __launch_bounds__(512, 2) void down_kernel(
    const __bf16* __restrict__ hbuf, const __bf16* __restrict__ Dt,
    const int* __restrict__ ctrl, float* __restrict__ ybuf)
{
    int bid = blockIdx.x;
    int swz = (bid & 7) * (MAXMB * 6 / 8) + (bid >> 3);   // 432 % 8 == 0
    int mb = swz / 6, y = swz - mb * 6;
    if (mb >= ctrl[24]) return;
    int e = ctrl[32 + mb];
    int dbase = y * 128;
    const __bf16* Dn = Dt + (size_t)e * DDIM * HDIM;   // [D][H]

    __shared__ __bf16 lds[3 * 16384];   // 96 KB: [buf][A|B][128*64]

    int tid = threadIdx.x;
    int lane = tid & 63, w = tid >> 6;
    int wr = w >> 2, wc = w & 3;

    int lr = tid >> 3;
    int lc = ((tid & 7) ^ (lr & 7)) << 3;
    const __bf16* gA0 = hbuf + (size_t)(mb * MBLK + lr) * HDIM + lc;
    const __bf16* gB0 = Dn + (size_t)(dbase + lr) * HDIM + lc;
    const size_t astep = (size_t)64 * HDIM;

    f32x4 acc[4][2];
#pragma unroll
    for (int m = 0; m < 4; m++)
#pragma unroll
        for (int n = 0; n < 2; n++) acc[m][n] = (f32x4)0.0f;

    auto stageA = [&](int buf, int kk) {   // A0, A1
        __bf16* d = &lds[buf * 16384];
        GLOAD16(gA0 + kk, d + tid * 8);
        GLOAD16(gA0 + kk + astep, d + 4096 + tid * 8);
    };
    auto stageB = [&](int buf, int kk) {   // B0, B1
        __bf16* d = &lds[buf * 16384];
        GLOAD16(gB0 + kk, d + 8192 + tid * 8);
        GLOAD16(gB0 + kk + astep, d + 12288 + tid * 8);
    };
    auto rdfrags = [&](const __bf16* A, const __bf16* B, int ks,
                       bf16x8* af, bf16x8* bd) {
        int kb = ks * 32 + (lane >> 4) * 8;
#pragma unroll
        for (int m = 0; m < 4; m++) {
            int row = wr * 64 + m * 16 + (lane & 15);
            af[m] = *reinterpret_cast<const bf16x8*>(&A[row * 64 + (kb ^ ((row & 7) << 3))]);
        }
#pragma unroll
        for (int n = 0; n < 2; n++) {
            int col = wc * 32 + n * 16 + (lane & 15);
            bd[n] = *reinterpret_cast<const bf16x8*>(&B[col * 64 + (kb ^ ((col & 7) << 3))]);
        }
    };
    auto domfma = [&](bf16x8* af, bf16x8* bd) {
        __builtin_amdgcn_s_setprio(1);
#pragma unroll
        for (int n = 0; n < 2; n++)
#pragma unroll
            for (int m = 0; m < 4; m++)
                acc[m][n] = MFMA_BF16(af[m], bd[n], acc[m][n], 0, 0, 0);
        __builtin_amdgcn_s_setprio(0);
    };

    stageA(0, 0);   stageB(0, 0);
    stageA(1, 64);  stageB(1, 64);
    SFENCE();
    VMWAIT(4);
    SFENCE();
    BAR();
    SFENCE();

#pragma unroll
    for (int t = 0; t < 24; ++t) {
        const __bf16* A = &lds[(t % 3) * 16384];
        const __bf16* B = A + 8192;
        int kk2 = (t + 2) * 64;
        bf16x8 af[4], bd[2];

        // ---- phase 0 (ks=0)
        rdfrags(A, B, 0, af, bd);
        if (t < 22) stageA((t + 2) % 3, kk2);
        SFENCE();
        BAR();
        LGKM0();
        SFENCE();
        domfma(af, bd);
        SFENCE();
        BAR();
        SFENCE();

        // ---- phase 1 (ks=1)
        rdfrags(A, B, 1, af, bd);
        if (t < 22) stageB((t + 2) % 3, kk2);
        SFENCE();
        if (t < 22) { VMWAIT(4); } else if (t == 22) { VMWAIT(0); }
        SFENCE();
        BAR();
        LGKM0();
        SFENCE();
        domfma(af, bd);
        SFENCE();
        BAR();
        SFENCE();
    }

#pragma unroll
    for (int m = 0; m < 4; m++)
#pragma unroll
        for (int n = 0; n < 2; n++)
#pragma unroll
            for (int r = 0; r < 4; r++) {
                int row = wr * 64 + m * 16 + (lane >> 4) * 4 + r;
                int col = dbase + wc * 32 + n * 16 + (lane & 15);
                ybuf[(size_t)(mb * MBLK + row) * DDIM + col] = acc[m][n][r];
            }
}

// combine: out[t] = w0*y[s0] + w1*y[s1]; fully overwrites d_out.
__global__ __launch_bounds__(192) void combine_kernel(
    const float* __restrict__ ybuf, const int* __restrict__ slot_of,
    const float* __restrict__ topk_w, float* __restrict__ out)
{
    int t = blockIdx.x;
    int q = threadIdx.x;
    int s0 = slot_of[2*t], s1 = slot_of[2*t+1];
    float w0 = topk_w[2*t], w1 = topk_w[2*t+1];
    f32x4 y0 = reinterpret_cast<const f32x4*>(ybuf + (size_t)s0 * DDIM)[q];
    f32x4 y1 = reinterpret_cast<const f32x4*>(ybuf + (size_t)s1 * DDIM)[q];
    f32x4 o;
#pragma unroll
    for (int r = 0; r < 4; r++) o[r] = w0 * y0[r] + w1 * y1[r];
    reinterpret_cast<f32x4*>(out + (size_t)t * DDIM)[q] = o;
}

// ---------------- launch ----------------
extern "C" void kernel_launch(void* const* d_in, const int* in_sizes, int n_in,
                              void* d_out, int out_size, void* d_ws, size_t ws_size,
                              hipStream_t stream)
{
    if (ws_size < WS_NEEDED) return;

    const float* x      = (const float*)d_in[0];
    const float* gate_w = (const float*)d_in[1];
    const float* gbank  = (const float*)d_in[2];
    const float* ubank  = (const float*)d_in[3];
    const float* dbank  = (const float*)d_in[4];
    float* out = (float*)d_out;

    char* ws = (char*)d_ws;
    __bf16* xb   = (__bf16*)(ws + XB_OFF);
    __bf16* Gt   = (__bf16*)(ws + GT_OFF);
    __bf16* Ut   = (__bf16*)(ws + UT_OFF);
    float*  ybuf = (float*)(ws + YB_OFF);
    __bf16* Dt   = (__bf16*)(ws + DT_OFF);
    __bf16* hbuf = (__bf16*)(ws + HB_OFF);
    int*    tki  = (int*)(ws + TKI_OFF);
    float*  tkw  = (float*)(ws + TKW_OFF);
    int*    pt   = (int*)(ws + PT_OFF);
    int*    slot = (int*)(ws + SL_OFF);
    int*    ctrl = (int*)(ws + CTRL_OFF);

    convert_x_kernel<<<(NTOK * DDIM / 4 + 255) / 256, 256, 0, stream>>>(x, xb, NTOK * DDIM / 4);

    // gate_bank [E][768][1536] -> Gt [E][1536][768]
    transpose64_kernel<<<dim3(HDIM/64, DDIM/64, EEXP), 256, 0, stream>>>(gbank, Gt, DDIM, HDIM);
    transpose64_kernel<<<dim3(HDIM/64, DDIM/64, EEXP), 256, 0, stream>>>(ubank, Ut, DDIM, HDIM);
    // down_bank [E][1536][768] -> Dt [E][768][1536]
    transpose64_kernel<<<dim3(DDIM/64, HDIM/64, EEXP), 256, 0, stream>>>(dbank, Dt, HDIM, DDIM);

    gating_kernel<<<NTOK / 4, 256, 0, stream>>>(x, gate_w, tki, tkw);
    route_kernel<<<1, RTHREADS, 0, stream>>>(tki, ctrl, pt, slot);

    gateup_kernel<<<MAXMB * (HDIM / 128), 512, 0, stream>>>(xb, Gt, Ut, ctrl, pt, hbuf);
    down_kernel<<<MAXMB * (DDIM / 128), 512, 0, stream>>>(hbuf, Dt, ctrl, ybuf);
    combine_kernel<<<NTOK, 192, 0, stream>>>(ybuf, slot, tkw, out);
}

// Round 8
// 140.571 us; speedup vs baseline: 1.0812x; 1.0796x over previous
//
#include <hip/hip_runtime.h>
#include <hip/hip_bf16.h>

// Problem constants (B=2, T=2048, D=768, E=8, H=1536, K=2)
#define NTOK 4096
#define DDIM 768
#define EEXP 8
#define HDIM 1536
#define MBLK 128
#define MAXMB 72            // sum ceil(cnt_e/128) <= 64+7, +margin
#define CAP  (MAXMB * MBLK) // 9216
#define NENT (NTOK * 2)     // 8192 routed (token,k) entries
#define RTHREADS 1024
#define EPT (NENT / RTHREADS) // 8 entries per route thread

typedef float f32x4 __attribute__((ext_vector_type(4)));
typedef __bf16 bf16x8 __attribute__((ext_vector_type(8)));
typedef __bf16 bf16x4 __attribute__((ext_vector_type(4)));

// ---------------- workspace layout (bytes) ----------------
static const size_t XB_OFF   = 0;                       // bf16 x [NTOK][D]      6,291,456
static const size_t GT_OFF   = 6291456;                 // bf16 Gt [E][H][D]    18,874,368
static const size_t UT_OFF   = GT_OFF + 18874368;       // bf16 Ut [E][H][D]    18,874,368
static const size_t YB_OFF   = GT_OFF;                  // f32 ybuf [CAP][D]    28,311,552 (aliases Gt+Ut, dead after gateup)
static const size_t DT_OFF   = UT_OFF + 18874368;       // bf16 Dt [E][D][H]    18,874,368
static const size_t HB_OFF   = DT_OFF + 18874368;       // bf16 h  [CAP][H]     28,311,552
static const size_t TKI_OFF  = HB_OFF + 28311552;       // int  topk_idx [NENT]
static const size_t TKW_OFF  = TKI_OFF + NENT*4;        // f32  topk_w   [NENT]
static const size_t PT_OFF   = TKW_OFF + NENT*4;        // int  pair_token [CAP]
static const size_t SL_OFF   = PT_OFF + CAP*4;          // int  slot_of  [NENT]
static const size_t CTRL_OFF = SL_OFF + NENT*4;
static const size_t WS_NEEDED = CTRL_OFF + 1024;

#define GLOAD16(g, l) __builtin_amdgcn_global_load_lds( \
    (const __attribute__((address_space(1))) void*)(g),  \
    (__attribute__((address_space(3))) void*)(l), 16, 0, 0)

#define MFMA_BF16 __builtin_amdgcn_mfma_f32_16x16x32_bf16

// T2 swizzle: LDS rows are 64 bf16 (128 B) = 8 units of 16 B. Stored unit =
// src_unit ^ (row&7); read addr = row*64 + (kb ^ ((row&7)<<3)). Verified:
// a wave b128 read puts exactly 8 lanes on each 4-bank quad (optimal).
// Staging pre-swizzles the GLOBAL source column; LDS write stays linear
// (global_load_lds constraint).

// ---------------- small kernels ----------------

__global__ __launch_bounds__(256) void convert_x_kernel(
    const float* __restrict__ x, __bf16* __restrict__ xb, int n4)
{
    int i = blockIdx.x * 256 + threadIdx.x;
    if (i < n4) {
        f32x4 v = reinterpret_cast<const f32x4*>(x)[i];
        bf16x4 o;
        o[0] = (__bf16)v[0]; o[1] = (__bf16)v[1];
        o[2] = (__bf16)v[2]; o[3] = (__bf16)v[3];
        reinterpret_cast<bf16x4*>(xb)[i] = o;
    }
}

// all three weight-bank transposes in one launch.
// z = bank*8 + e; bank 0: gbank 768x1536 -> Gt; 1: ubank -> Ut; 2: dbank 1536x768 -> Dt
__global__ __launch_bounds__(256) void transpose_all_kernel(
    const float* __restrict__ gb, const float* __restrict__ ub,
    const float* __restrict__ db, __bf16* __restrict__ Gt,
    __bf16* __restrict__ Ut, __bf16* __restrict__ Dt)
{
    __shared__ float tile[64][65];
    int z = blockIdx.z, bank = z >> 3, e = z & 7;
    int R, C, r0, c0;
    const float* s;
    __bf16* d;
    if (bank < 2) {
        R = DDIM; C = HDIM;
        s = (bank == 0 ? gb : ub) + (size_t)e * DDIM * HDIM;
        d = (bank == 0 ? Gt : Ut) + (size_t)e * DDIM * HDIM;
        c0 = blockIdx.x * 64; r0 = blockIdx.y * 64;   // x:24, y:12
    } else {
        R = HDIM; C = DDIM;
        s = db + (size_t)e * DDIM * HDIM;
        d = Dt + (size_t)e * DDIM * HDIM;
        r0 = blockIdx.x * 64; c0 = blockIdx.y * 64;   // x:24, y:12
    }
    int tx = threadIdx.x & 15, ty = threadIdx.x >> 4;   // 16 x 16
#pragma unroll
    for (int j = 0; j < 4; j++) {
        int r = ty + j * 16;
        f32x4 v = *reinterpret_cast<const f32x4*>(&s[(size_t)(r0 + r) * C + c0 + tx * 4]);
        tile[r][tx*4+0] = v[0]; tile[r][tx*4+1] = v[1];
        tile[r][tx*4+2] = v[2]; tile[r][tx*4+3] = v[3];
    }
    __syncthreads();
#pragma unroll
    for (int j = 0; j < 4; j++) {
        int c = ty + j * 16;
        bf16x4 o;
#pragma unroll
        for (int i = 0; i < 4; i++) o[i] = (__bf16)tile[tx*4+i][c];
        *reinterpret_cast<bf16x4*>(&d[(size_t)(c0 + c) * R + r0 + tx*4]) = o;
    }
}

// one wave per token: 8 dots of length 768, softmax, top-2, normalized weights.
// NO atomics (8-address atomic contention serialized the whole kernel).
__global__ __launch_bounds__(256) void gating_kernel(
    const float* __restrict__ x, const float* __restrict__ gw,
    int* __restrict__ topk_idx, float* __restrict__ topk_w)
{
    int lane = threadIdx.x & 63;
    int t = blockIdx.x * 4 + (threadIdx.x >> 6);
    const float* xr = x + (size_t)t * DDIM;
    float acc[EEXP];
#pragma unroll
    for (int e = 0; e < EEXP; e++) acc[e] = 0.0f;
    for (int i = 0; i < DDIM / 64; i++) {
        int d = lane + i * 64;
        float xv = xr[d];
#pragma unroll
        for (int e = 0; e < EEXP; e++) acc[e] += xv * gw[e * DDIM + d];
    }
#pragma unroll
    for (int e = 0; e < EEXP; e++) {
        for (int off = 32; off; off >>= 1) acc[e] += __shfl_xor(acc[e], off);
    }
    if (lane == 0) {
        float m = acc[0];
#pragma unroll
        for (int e = 1; e < EEXP; e++) m = fmaxf(m, acc[e]);
        float p[EEXP], sum = 0.0f;
#pragma unroll
        for (int e = 0; e < EEXP; e++) { p[e] = expf(acc[e] - m); sum += p[e]; }
        int i0 = 0; float b0 = acc[0];
#pragma unroll
        for (int e = 1; e < EEXP; e++) if (acc[e] > b0) { b0 = acc[e]; i0 = e; }
        int i1 = -1; float b1 = -3.4e38f;
#pragma unroll
        for (int e = 0; e < EEXP; e++) if (e != i0 && acc[e] > b1) { b1 = acc[e]; i1 = e; }
        float pr0 = p[i0] / sum, pr1 = p[i1] / sum;
        float den = pr0 + pr1 + 1e-8f;
        topk_idx[2*t]   = i0; topk_w[2*t]   = pr0 / den;
        topk_idx[2*t+1] = i1; topk_w[2*t+1] = pr1 / den;
    }
}

// single-block deterministic routing: zero-init pads + counts + 128-aligned
// offsets + mblock table + slot assignment via shfl/LDS prefix scans. No atomics.
__global__ __launch_bounds__(RTHREADS) void route_kernel(
    const int* __restrict__ topk_idx, int* __restrict__ ctrl,
    int* __restrict__ pair_token, int* __restrict__ slot_of)
{
    __shared__ int wt[EEXP][16];    // per-wave totals
    __shared__ int wpre[EEXP][16];  // exclusive prefix of wave totals
    __shared__ int base[EEXP];      // 128-aligned expert base slot

    int tid = threadIdx.x;
    int lane = tid & 63, wv = tid >> 6;

    // zero pad slots (poisoned ws would otherwise feed garbage token indices)
    for (int i = tid; i < CAP; i += RTHREADS) pair_token[i] = 0;

    int e_of[EPT];
    int c[EEXP];
#pragma unroll
    for (int e = 0; e < EEXP; e++) c[e] = 0;
#pragma unroll
    for (int j = 0; j < EPT; j++) {
        int e = topk_idx[tid * EPT + j];
        e_of[j] = e;
        c[e]++;
    }

    // per-expert exclusive prefix within wave + wave total
    int pre[EEXP];
#pragma unroll
    for (int e = 0; e < EEXP; e++) {
        int v = c[e];
        for (int d = 1; d < 64; d <<= 1) {
            int u = __shfl_up(v, d);
            if (lane >= d) v += u;
        }
        pre[e] = v - c[e];
        if (lane == 63) wt[e][wv] = v;
    }
    __syncthreads();

    if (tid == 0) {
        int off = 0, gmb = 0;
        for (int e = 0; e < EEXP; e++) {
            int run = 0;
            for (int w = 0; w < 16; w++) { wpre[e][w] = run; run += wt[e][w]; }
            base[e] = off;
            int nmb = (run + MBLK - 1) >> 7;
            for (int i = 0; i < nmb; i++) ctrl[32 + gmb++] = e;
            off += nmb << 7;
        }
        ctrl[24] = gmb;
    }
    __syncthreads();

    int run[EEXP];
#pragma unroll
    for (int e = 0; e < EEXP; e++) run[e] = base[e] + wpre[e][wv] + pre[e];
#pragma unroll
    for (int j = 0; j < EPT; j++) {
        int ent = tid * EPT + j;
        int e = e_of[j];
        int slot = run[e]++;
        pair_token[slot] = ent >> 1;
        slot_of[ent] = slot;
    }
}

// ------- gate/up fused GEMM: m97 structure, 64x64 wave tiles + T2 swizzle -------
// Tile 128x128, BK=64, K=768 (12 steps). 256 thr = 4 waves (2x2), wave 64x64.
// LDS: A 16K + Bg 16K + Bu 16K = 48 KB single-buffer -> 2 blocks/CU; cross-block
// wave overlap hides the barrier drain (m97/m114 mechanism).
__global__ __launch_bounds__(256, 2) void gateup_kernel(
    const __bf16* __restrict__ xb, const __bf16* __restrict__ Gt,
    const __bf16* __restrict__ Ut, const int* __restrict__ ctrl,
    const int* __restrict__ pair_token, __bf16* __restrict__ hbuf)
{
    // flattened grid, y-fastest; bijective XCD chunk swizzle (864 % 8 == 0)
    int bid = blockIdx.x;
    int swz = (bid & 7) * (MAXMB * 12 / 8) + (bid >> 3);
    int mb = swz / 12, y = swz - mb * 12;
    if (mb >= ctrl[24]) return;
    int e = ctrl[32 + mb];
    int hbase = y * 128;
    const __bf16* G = Gt + (size_t)e * HDIM * DDIM;   // [H][D]
    const __bf16* U = Ut + (size_t)e * HDIM * DDIM;

    __shared__ __bf16 lds[3 * 8192];   // 48 KB: A | Bg | Bu, each [128][64]

    int tid = threadIdx.x;
    int lane = tid & 63, w = tid >> 6;
    int wr = w >> 1, wc = w & 1;

    // staging: one GLOAD16 x 256 thr = 4 KB = 32 rows x 128 B.
    int lr = tid >> 3;                        // row in 32-row chunk
    int lc = ((tid & 7) ^ (lr & 7)) << 3;     // pre-swizzled source col elem
    const __bf16* gA[4];
#pragma unroll
    for (int j = 0; j < 4; j++) {
        int tok = pair_token[mb * MBLK + j * 32 + lr];
        gA[j] = xb + (size_t)tok * DDIM + lc;
    }
    const __bf16* gG = G + (size_t)(hbase + lr) * DDIM + lc;   // + j*32 rows
    const __bf16* gU = U + (size_t)(hbase + lr) * DDIM + lc;
    const size_t rstep = (size_t)32 * DDIM;

    f32x4 accg[4][4], accu[4][4];
#pragma unroll
    for (int m = 0; m < 4; m++)
#pragma unroll
        for (int n = 0; n < 4; n++) { accg[m][n] = (f32x4)0.0f; accu[m][n] = (f32x4)0.0f; }

    for (int kk = 0; kk < DDIM; kk += 64) {
#pragma unroll
        for (int j = 0; j < 4; j++)
            GLOAD16(gA[j] + kk, &lds[j * 2048 + tid * 8]);
#pragma unroll
        for (int j = 0; j < 4; j++)
            GLOAD16(gG + kk + j * rstep, &lds[8192 + j * 2048 + tid * 8]);
#pragma unroll
        for (int j = 0; j < 4; j++)
            GLOAD16(gU + kk + j * rstep, &lds[16384 + j * 2048 + tid * 8]);
        __syncthreads();

#pragma unroll
        for (int ks = 0; ks < 2; ks++) {
            int kb = ks * 32 + (lane >> 4) * 8;
            bf16x8 af[4], bg[4], bu[4];
#pragma unroll
            for (int m = 0; m < 4; m++) {
                int row = wr * 64 + m * 16 + (lane & 15);
                af[m] = *reinterpret_cast<const bf16x8*>(
                    &lds[row * 64 + (kb ^ ((row & 7) << 3))]);
            }
#pragma unroll
            for (int n = 0; n < 4; n++) {
                int col = wc * 64 + n * 16 + (lane & 15);
                int ba = col * 64 + (kb ^ ((col & 7) << 3));
                bg[n] = *reinterpret_cast<const bf16x8*>(&lds[8192 + ba]);
                bu[n] = *reinterpret_cast<const bf16x8*>(&lds[16384 + ba]);
            }
#pragma unroll
            for (int n = 0; n < 4; n++)
#pragma unroll
                for (int m = 0; m < 4; m++) {
                    accg[m][n] = MFMA_BF16(af[m], bg[n], accg[m][n], 0, 0, 0);
                    accu[m][n] = MFMA_BF16(af[m], bu[n], accu[m][n], 0, 0, 0);
                }
        }
        __syncthreads();
    }

    size_t slotbase = (size_t)mb * MBLK;
#pragma unroll
    for (int m = 0; m < 4; m++)
#pragma unroll
        for (int n = 0; n < 4; n++)
#pragma unroll
            for (int r = 0; r < 4; r++) {
                int row = wr * 64 + m * 16 + (lane >> 4) * 4 + r;
                int col = hbase + wc * 64 + n * 16 + (lane & 15);
                float a = accg[m][n][r], u = accu[m][n][r];
                float hv = (a / (1.0f + expf(-a))) * u;
                hbuf[(slotbase + row) * HDIM + col] = (__bf16)hv;
            }
}

// ------- down GEMM: m97 structure, 64x64 wave tiles + T2 swizzle -------
// Tile 128x128, BK=64, K=1536 (24 steps). 256 thr = 4 waves (2x2).
// LDS: A 16K + B 16K = 32 KB single-buffer; launch_bounds(256,3) -> 3 blocks/CU.
__global__ __launch_bounds__(256, 3) void down_kernel(
    const __bf16* __restrict__ hbuf, const __bf16* __restrict__ Dt,
    const int* __restrict__ ctrl, float* __restrict__ ybuf)
{
    int bid = blockIdx.x;
    int swz = (bid & 7) * (MAXMB * 6 / 8) + (bid >> 3);   // 432 % 8 == 0
    int mb = swz / 6, y = swz - mb * 6;
    if (mb >= ctrl[24]) return;
    int e = ctrl[32 + mb];
    int dbase = y * 128;
    const __bf16* Dn = Dt + (size_t)e * DDIM * HDIM;   // [D][H]

    __shared__ __bf16 lds[2 * 8192];   // 32 KB: A | B

    int tid = threadIdx.x;
    int lane = tid & 63, w = tid >> 6;
    int wr = w >> 1, wc = w & 1;

    int lr = tid >> 3;
    int lc = ((tid & 7) ^ (lr & 7)) << 3;
    const __bf16* gA = hbuf + (size_t)(mb * MBLK + lr) * HDIM + lc;   // + j*32 rows
    const __bf16* gB = Dn + (size_t)(dbase + lr) * HDIM + lc;
    const size_t rstep = (size_t)32 * HDIM;

    f32x4 acc[4][4];
#pragma unroll
    for (int m = 0; m < 4; m++)
#pragma unroll
        for (int n = 0; n < 4; n++) acc[m][n] = (f32x4)0.0f;

    for (int kk = 0; kk < HDIM; kk += 64) {
#pragma unroll
        for (int j = 0; j < 4; j++)
            GLOAD16(gA + kk + j * rstep, &lds[j * 2048 + tid * 8]);
#pragma unroll
        for (int j = 0; j < 4; j++)
            GLOAD16(gB + kk + j * rstep, &lds[8192 + j * 2048 + tid * 8]);
        __syncthreads();

#pragma unroll
        for (int ks = 0; ks < 2; ks++) {
            int kb = ks * 32 + (lane >> 4) * 8;
            bf16x8 af[4], bd[4];
#pragma unroll
            for (int m = 0; m < 4; m++) {
                int row = wr * 64 + m * 16 + (lane & 15);
                af[m] = *reinterpret_cast<const bf16x8*>(
                    &lds[row * 64 + (kb ^ ((row & 7) << 3))]);
            }
#pragma unroll
            for (int n = 0; n < 4; n++) {
                int col = wc * 64 + n * 16 + (lane & 15);
                bd[n] = *reinterpret_cast<const bf16x8*>(
                    &lds[8192 + col * 64 + (kb ^ ((col & 7) << 3))]);
            }
#pragma unroll
            for (int n = 0; n < 4; n++)
#pragma unroll
                for (int m = 0; m < 4; m++)
                    acc[m][n] = MFMA_BF16(af[m], bd[n], acc[m][n], 0, 0, 0);
        }
        __syncthreads();
    }

#pragma unroll
    for (int m = 0; m < 4; m++)
#pragma unroll
        for (int n = 0; n < 4; n++)
#pragma unroll
            for (int r = 0; r < 4; r++) {
                int row = wr * 64 + m * 16 + (lane >> 4) * 4 + r;
                int col = dbase + wc * 64 + n * 16 + (lane & 15);
                ybuf[(size_t)(mb * MBLK + row) * DDIM + col] = acc[m][n][r];
            }
}

// combine: out[t] = w0*y[s0] + w1*y[s1]; fully overwrites d_out.
__global__ __launch_bounds__(192) void combine_kernel(
    const float* __restrict__ ybuf, const int* __restrict__ slot_of,
    const float* __restrict__ topk_w, float* __restrict__ out)
{
    int t = blockIdx.x;
    int q = threadIdx.x;
    int s0 = slot_of[2*t], s1 = slot_of[2*t+1];
    float w0 = topk_w[2*t], w1 = topk_w[2*t+1];
    f32x4 y0 = reinterpret_cast<const f32x4*>(ybuf + (size_t)s0 * DDIM)[q];
    f32x4 y1 = reinterpret_cast<const f32x4*>(ybuf + (size_t)s1 * DDIM)[q];
    f32x4 o;
#pragma unroll
    for (int r = 0; r < 4; r++) o[r] = w0 * y0[r] + w1 * y1[r];
    reinterpret_cast<f32x4*>(out + (size_t)t * DDIM)[q] = o;
}

// ---------------- launch ----------------
extern "C" void kernel_launch(void* const* d_in, const int* in_sizes, int n_in,
                              void* d_out, int out_size, void* d_ws, size_t ws_size,
                              hipStream_t stream)
{
    if (ws_size < WS_NEEDED) return;

    const float* x      = (const float*)d_in[0];
    const float* gate_w = (const float*)d_in[1];
    const float* gbank  = (const float*)d_in[2];
    const float* ubank  = (const float*)d_in[3];
    const float* dbank  = (const float*)d_in[4];
    float* out = (float*)d_out;

    char* ws = (char*)d_ws;
    __bf16* xb   = (__bf16*)(ws + XB_OFF);
    __bf16* Gt   = (__bf16*)(ws + GT_OFF);
    __bf16* Ut   = (__bf16*)(ws + UT_OFF);
    float*  ybuf = (float*)(ws + YB_OFF);
    __bf16* Dt   = (__bf16*)(ws + DT_OFF);
    __bf16* hbuf = (__bf16*)(ws + HB_OFF);
    int*    tki  = (int*)(ws + TKI_OFF);
    float*  tkw  = (float*)(ws + TKW_OFF);
    int*    pt   = (int*)(ws + PT_OFF);
    int*    slot = (int*)(ws + SL_OFF);
    int*    ctrl = (int*)(ws + CTRL_OFF);

    convert_x_kernel<<<(NTOK * DDIM / 4 + 255) / 256, 256, 0, stream>>>(x, xb, NTOK * DDIM / 4);
    transpose_all_kernel<<<dim3(24, 12, 24), 256, 0, stream>>>(gbank, ubank, dbank, Gt, Ut, Dt);

    gating_kernel<<<NTOK / 4, 256, 0, stream>>>(x, gate_w, tki, tkw);
    route_kernel<<<1, RTHREADS, 0, stream>>>(tki, ctrl, pt, slot);

    gateup_kernel<<<MAXMB * (HDIM / 128), 256, 0, stream>>>(xb, Gt, Ut, ctrl, pt, hbuf);
    down_kernel<<<MAXMB * (DDIM / 128), 256, 0, stream>>>(hbuf, Dt, ctrl, ybuf);
    combine_kernel<<<NTOK, 192, 0, stream>>>(ybuf, slot, tkw, out);
}

// Round 9
// 125.394 us; speedup vs baseline: 1.2121x; 1.1210x over previous
//
#include <hip/hip_runtime.h>
#include <hip/hip_bf16.h>

// Problem constants (B=2, T=2048, D=768, E=8, H=1536, K=2)
#define NTOK 4096
#define DDIM 768
#define EEXP 8
#define HDIM 1536
#define MBLK 128
#define MAXMB 72            // sum ceil(cnt_e/128) <= 64+7, +margin
#define CAP  (MAXMB * MBLK) // 9216
#define NENT (NTOK * 2)     // 8192 routed (token,k) entries
#define RTHREADS 1024
#define EPT (NENT / RTHREADS) // 8 entries per route thread
#define NTTILE 6912           // transpose tiles: 24 z-banks * 288

typedef float f32x4 __attribute__((ext_vector_type(4)));
typedef __bf16 bf16x8 __attribute__((ext_vector_type(8)));
typedef __bf16 bf16x4 __attribute__((ext_vector_type(4)));

// ---------------- workspace layout (bytes) ----------------
static const size_t XB_OFF   = 0;                       // bf16 x [NTOK][D]      6,291,456
static const size_t GT_OFF   = 6291456;                 // bf16 Gt [E][H][D]    18,874,368
static const size_t UT_OFF   = GT_OFF + 18874368;       // bf16 Ut [E][H][D]    18,874,368
static const size_t YB_OFF   = GT_OFF;                  // f32 ybuf [CAP][D]    28,311,552 (aliases Gt+Ut, dead after gateup)
static const size_t DT_OFF   = UT_OFF + 18874368;       // bf16 Dt [E][D][H]    18,874,368
static const size_t HB_OFF   = DT_OFF + 18874368;       // bf16 h  [CAP][H]     28,311,552
static const size_t TKI_OFF  = HB_OFF + 28311552;       // int  topk_idx [NENT]
static const size_t TKW_OFF  = TKI_OFF + NENT*4;        // f32  topk_w   [NENT]
static const size_t PT_OFF   = TKW_OFF + NENT*4;        // int  pair_token [CAP]
static const size_t SL_OFF   = PT_OFF + CAP*4;          // int  slot_of  [NENT]
static const size_t CTRL_OFF = SL_OFF + NENT*4;
static const size_t WS_NEEDED = CTRL_OFF + 1024;

#define GLOAD16(g, l) __builtin_amdgcn_global_load_lds( \
    (const __attribute__((address_space(1))) void*)(g),  \
    (__attribute__((address_space(3))) void*)(l), 16, 0, 0)

#define MFMA_BF16 __builtin_amdgcn_mfma_f32_16x16x32_bf16

// T2 swizzle: LDS rows are 64 bf16 (128 B) = 8 units of 16 B. Stored unit =
// src_unit ^ (row&7); read addr = row*64 + (kb ^ ((row&7)<<3)). A wave b128
// read puts exactly 8 lanes on each 4-bank quad (conflict-free, verified r5+).
// Staging pre-swizzles the GLOBAL source column; LDS write stays linear
// (global_load_lds constraint).

// ---------------- gating + x-convert (fused: x read once) ----------------
// one wave per token: 8 dots of length 768, softmax, top-2, normalized weights;
// also emits xb = bf16(x). NO atomics.
__global__ __launch_bounds__(256) void gating_kernel(
    const float* __restrict__ x, const float* __restrict__ gw,
    int* __restrict__ topk_idx, float* __restrict__ topk_w,
    __bf16* __restrict__ xb)
{
    int lane = threadIdx.x & 63;
    int t = blockIdx.x * 4 + (threadIdx.x >> 6);
    const float* xr = x + (size_t)t * DDIM;
    __bf16* xbr = xb + (size_t)t * DDIM;
    float acc[EEXP];
#pragma unroll
    for (int e = 0; e < EEXP; e++) acc[e] = 0.0f;
#pragma unroll
    for (int i = 0; i < DDIM / 64; i++) {
        int d = lane + i * 64;
        float xv = xr[d];
        xbr[d] = (__bf16)xv;            // fused convert (coalesced 128B/wave)
#pragma unroll
        for (int e = 0; e < EEXP; e++) acc[e] += xv * gw[e * DDIM + d];
    }
#pragma unroll
    for (int e = 0; e < EEXP; e++) {
        for (int off = 32; off; off >>= 1) acc[e] += __shfl_xor(acc[e], off);
    }
    if (lane == 0) {
        float m = acc[0];
#pragma unroll
        for (int e = 1; e < EEXP; e++) m = fmaxf(m, acc[e]);
        float p[EEXP], sum = 0.0f;
#pragma unroll
        for (int e = 0; e < EEXP; e++) { p[e] = expf(acc[e] - m); sum += p[e]; }
        int i0 = 0; float b0 = acc[0];
#pragma unroll
        for (int e = 1; e < EEXP; e++) if (acc[e] > b0) { b0 = acc[e]; i0 = e; }
        int i1 = -1; float b1 = -3.4e38f;
#pragma unroll
        for (int e = 0; e < EEXP; e++) if (e != i0 && acc[e] > b1) { b1 = acc[e]; i1 = e; }
        float pr0 = p[i0] / sum, pr1 = p[i1] / sum;
        float den = pr0 + pr1 + 1e-8f;
        topk_idx[2*t]   = i0; topk_w[2*t]   = pr0 / den;
        topk_idx[2*t+1] = i1; topk_w[2*t+1] = pr1 / den;
    }
}

// ---------------- mega: weight transposes + routing in ONE launch ----------------
// block 0 = route (runs first, hides under the BW-bound transpose blocks).
// blocks 1..NTTILE = 64x64 transpose tiles, 1024 threads each.
__global__ __launch_bounds__(RTHREADS) void mega_kernel(
    const float* __restrict__ gb, const float* __restrict__ ub,
    const float* __restrict__ db, __bf16* __restrict__ Gt,
    __bf16* __restrict__ Ut, __bf16* __restrict__ Dt,
    const int* __restrict__ topk_idx, int* __restrict__ ctrl,
    int* __restrict__ pair_token, int* __restrict__ slot_of)
{
    __shared__ float tile[64][65];
    __shared__ int wt[EEXP][16];
    __shared__ int wpre[EEXP][16];
    __shared__ int base[EEXP];

    int tid = threadIdx.x;

    if (blockIdx.x == 0) {
        // ---- deterministic routing: zero pads + prefix scans, no atomics ----
        int lane = tid & 63, wv = tid >> 6;
        for (int i = tid; i < CAP; i += RTHREADS) pair_token[i] = 0;

        int e_of[EPT];
        int c[EEXP];
#pragma unroll
        for (int e = 0; e < EEXP; e++) c[e] = 0;
#pragma unroll
        for (int j = 0; j < EPT; j++) {
            int e = topk_idx[tid * EPT + j];
            e_of[j] = e;
            c[e]++;
        }
        int pre[EEXP];
#pragma unroll
        for (int e = 0; e < EEXP; e++) {
            int v = c[e];
            for (int d = 1; d < 64; d <<= 1) {
                int u = __shfl_up(v, d);
                if (lane >= d) v += u;
            }
            pre[e] = v - c[e];
            if (lane == 63) wt[e][wv] = v;
        }
        __syncthreads();
        if (tid == 0) {
            int off = 0, gmb = 0;
            for (int e = 0; e < EEXP; e++) {
                int run = 0;
                for (int w = 0; w < 16; w++) { wpre[e][w] = run; run += wt[e][w]; }
                base[e] = off;
                int nmb = (run + MBLK - 1) >> 7;
                for (int i = 0; i < nmb; i++) ctrl[32 + gmb++] = e;
                off += nmb << 7;
            }
            ctrl[24] = gmb;
        }
        __syncthreads();
        int run[EEXP];
#pragma unroll
        for (int e = 0; e < EEXP; e++) run[e] = base[e] + wpre[e][wv] + pre[e];
#pragma unroll
        for (int j = 0; j < EPT; j++) {
            int ent = tid * EPT + j;
            int e = e_of[j];
            int slot = run[e]++;
            pair_token[slot] = ent >> 1;
            slot_of[ent] = slot;
        }
        return;
    }

    // ---- 64x64 transpose+convert tile ----
    int bt = blockIdx.x - 1;          // 0..6911
    int z = bt / 288, rem = bt - z * 288;
    int bank = z >> 3, e = z & 7;
    int R, C, r0, c0;
    const float* s;
    __bf16* d;
    if (bank < 2) {
        R = DDIM; C = HDIM;
        s = (bank == 0 ? gb : ub) + (size_t)e * DDIM * HDIM;
        d = (bank == 0 ? Gt : Ut) + (size_t)e * DDIM * HDIM;
        c0 = (rem % 24) * 64; r0 = (rem / 24) * 64;
    } else {
        R = HDIM; C = DDIM;
        s = db + (size_t)e * DDIM * HDIM;
        d = Dt + (size_t)e * DDIM * HDIM;
        r0 = (rem % 24) * 64; c0 = (rem / 24) * 64;
    }
    int tx = tid & 15, ty = tid >> 4;   // 16 x 64
    {
        f32x4 v = *reinterpret_cast<const f32x4*>(&s[(size_t)(r0 + ty) * C + c0 + tx * 4]);
        tile[ty][tx*4+0] = v[0]; tile[ty][tx*4+1] = v[1];
        tile[ty][tx*4+2] = v[2]; tile[ty][tx*4+3] = v[3];
    }
    __syncthreads();
    {
        bf16x4 o;
#pragma unroll
        for (int i = 0; i < 4; i++) o[i] = (__bf16)tile[tx*4+i][ty];
        *reinterpret_cast<bf16x4*>(&d[(size_t)(c0 + ty) * R + r0 + tx*4]) = o;
    }
}

// ------- gate/up fused GEMM: m97 structure, 64x64 wave tiles + T2 swizzle -------
// Tile 128x128, BK=64, K=768 (12 steps, FULLY UNROLLED: global offsets fold into
// 13-bit offset: immediates, LDS addrs hoisted -> VALU off the critical path).
// 256 thr = 4 waves (2x2), wave 64x64. LDS 48 KB -> 3 blocks/CU.
__global__ __launch_bounds__(256, 2) void gateup_kernel(
    const __bf16* __restrict__ xb, const __bf16* __restrict__ Gt,
    const __bf16* __restrict__ Ut, const int* __restrict__ ctrl,
    const int* __restrict__ pair_token, __bf16* __restrict__ hbuf)
{
    // flattened grid, y-fastest; bijective XCD chunk swizzle (864 % 8 == 0)
    int bid = blockIdx.x;
    int swz = (bid & 7) * (MAXMB * 12 / 8) + (bid >> 3);
    int mb = swz / 12, y = swz - mb * 12;
    if (mb >= ctrl[24]) return;
    int e = ctrl[32 + mb];
    int hbase = y * 128;
    const __bf16* G = Gt + (size_t)e * HDIM * DDIM;   // [H][D]
    const __bf16* U = Ut + (size_t)e * HDIM * DDIM;

    __shared__ __bf16 lds[3 * 8192];   // 48 KB: A | Bg | Bu, each [128][64]

    int tid = threadIdx.x;
    int lane = tid & 63, w = tid >> 6;
    int wr = w >> 1, wc = w & 1;

    // staging: one GLOAD16 x 256 thr = 4 KB = 32 rows x 128 B.
    int lr = tid >> 3;                        // row in 32-row chunk
    int lc = ((tid & 7) ^ (lr & 7)) << 3;     // pre-swizzled source col elem
    const __bf16* gA[4];
#pragma unroll
    for (int j = 0; j < 4; j++) {
        int tok = pair_token[mb * MBLK + j * 32 + lr];
        gA[j] = xb + (size_t)tok * DDIM + lc;
    }
    const __bf16* gG = G + (size_t)(hbase + lr) * DDIM + lc;   // + j*32 rows
    const __bf16* gU = U + (size_t)(hbase + lr) * DDIM + lc;
    const size_t rstep = (size_t)32 * DDIM;

    f32x4 accg[4][4], accu[4][4];
#pragma unroll
    for (int m = 0; m < 4; m++)
#pragma unroll
        for (int n = 0; n < 4; n++) { accg[m][n] = (f32x4)0.0f; accu[m][n] = (f32x4)0.0f; }

#pragma unroll
    for (int kt = 0; kt < DDIM / 64; kt++) {
        const int kk = kt * 64;
#pragma unroll
        for (int j = 0; j < 4; j++)
            GLOAD16(gA[j] + kk, &lds[j * 2048 + tid * 8]);
#pragma unroll
        for (int j = 0; j < 4; j++)
            GLOAD16(gG + kk + j * rstep, &lds[8192 + j * 2048 + tid * 8]);
#pragma unroll
        for (int j = 0; j < 4; j++)
            GLOAD16(gU + kk + j * rstep, &lds[16384 + j * 2048 + tid * 8]);
        __syncthreads();

#pragma unroll
        for (int ks = 0; ks < 2; ks++) {
            int kb = ks * 32 + (lane >> 4) * 8;
            bf16x8 af[4], bg[4], bu[4];
#pragma unroll
            for (int m = 0; m < 4; m++) {
                int row = wr * 64 + m * 16 + (lane & 15);
                af[m] = *reinterpret_cast<const bf16x8*>(
                    &lds[row * 64 + (kb ^ ((row & 7) << 3))]);
            }
#pragma unroll
            for (int n = 0; n < 4; n++) {
                int col = wc * 64 + n * 16 + (lane & 15);
                int ba = col * 64 + (kb ^ ((col & 7) << 3));
                bg[n] = *reinterpret_cast<const bf16x8*>(&lds[8192 + ba]);
                bu[n] = *reinterpret_cast<const bf16x8*>(&lds[16384 + ba]);
            }
#pragma unroll
            for (int n = 0; n < 4; n++)
#pragma unroll
                for (int m = 0; m < 4; m++) {
                    accg[m][n] = MFMA_BF16(af[m], bg[n], accg[m][n], 0, 0, 0);
                    accu[m][n] = MFMA_BF16(af[m], bu[n], accu[m][n], 0, 0, 0);
                }
        }
        __syncthreads();
    }

    size_t slotbase = (size_t)mb * MBLK;
#pragma unroll
    for (int m = 0; m < 4; m++)
#pragma unroll
        for (int n = 0; n < 4; n++)
#pragma unroll
            for (int r = 0; r < 4; r++) {
                int row = wr * 64 + m * 16 + (lane >> 4) * 4 + r;
                int col = hbase + wc * 64 + n * 16 + (lane & 15);
                float a = accg[m][n][r], u = accu[m][n][r];
                float hv = (a / (1.0f + expf(-a))) * u;
                hbuf[(slotbase + row) * HDIM + col] = (__bf16)hv;
            }
}

// ------- down GEMM: m97 structure, 64x64 wave tiles + T2 swizzle -------
// Tile 128x128, BK=64, K=1536 (24 steps, fully unrolled). 256 thr = 4 waves.
// LDS 32 KB single-buffer; 3+ blocks/CU.
__global__ __launch_bounds__(256, 3) void down_kernel(
    const __bf16* __restrict__ hbuf, const __bf16* __restrict__ Dt,
    const int* __restrict__ ctrl, float* __restrict__ ybuf)
{
    int bid = blockIdx.x;
    int swz = (bid & 7) * (MAXMB * 6 / 8) + (bid >> 3);   // 432 % 8 == 0
    int mb = swz / 6, y = swz - mb * 6;
    if (mb >= ctrl[24]) return;
    int e = ctrl[32 + mb];
    int dbase = y * 128;
    const __bf16* Dn = Dt + (size_t)e * DDIM * HDIM;   // [D][H]

    __shared__ __bf16 lds[2 * 8192];   // 32 KB: A | B

    int tid = threadIdx.x;
    int lane = tid & 63, w = tid >> 6;
    int wr = w >> 1, wc = w & 1;

    int lr = tid >> 3;
    int lc = ((tid & 7) ^ (lr & 7)) << 3;
    const __bf16* gA = hbuf + (size_t)(mb * MBLK + lr) * HDIM + lc;   // + j*32 rows
    const __bf16* gB = Dn + (size_t)(dbase + lr) * HDIM + lc;
    const size_t rstep = (size_t)32 * HDIM;

    f32x4 acc[4][4];
#pragma unroll
    for (int m = 0; m < 4; m++)
#pragma unroll
        for (int n = 0; n < 4; n++) acc[m][n] = (f32x4)0.0f;

#pragma unroll
    for (int kt = 0; kt < HDIM / 64; kt++) {
        const int kk = kt * 64;
#pragma unroll
        for (int j = 0; j < 4; j++)
            GLOAD16(gA + kk + j * rstep, &lds[j * 2048 + tid * 8]);
#pragma unroll
        for (int j = 0; j < 4; j++)
            GLOAD16(gB + kk + j * rstep, &lds[8192 + j * 2048 + tid * 8]);
        __syncthreads();

#pragma unroll
        for (int ks = 0; ks < 2; ks++) {
            int kb = ks * 32 + (lane >> 4) * 8;
            bf16x8 af[4], bd[4];
#pragma unroll
            for (int m = 0; m < 4; m++) {
                int row = wr * 64 + m * 16 + (lane & 15);
                af[m] = *reinterpret_cast<const bf16x8*>(
                    &lds[row * 64 + (kb ^ ((row & 7) << 3))]);
            }
#pragma unroll
            for (int n = 0; n < 4; n++) {
                int col = wc * 64 + n * 16 + (lane & 15);
                bd[n] = *reinterpret_cast<const bf16x8*>(
                    &lds[8192 + col * 64 + (kb ^ ((col & 7) << 3))]);
            }
#pragma unroll
            for (int n = 0; n < 4; n++)
#pragma unroll
                for (int m = 0; m < 4; m++)
                    acc[m][n] = MFMA_BF16(af[m], bd[n], acc[m][n], 0, 0, 0);
        }
        __syncthreads();
    }

#pragma unroll
    for (int m = 0; m < 4; m++)
#pragma unroll
        for (int n = 0; n < 4; n++)
#pragma unroll
            for (int r = 0; r < 4; r++) {
                int row = wr * 64 + m * 16 + (lane >> 4) * 4 + r;
                int col = dbase + wc * 64 + n * 16 + (lane & 15);
                ybuf[(size_t)(mb * MBLK + row) * DDIM + col] = acc[m][n][r];
            }
}

// combine: out[t] = w0*y[s0] + w1*y[s1]; fully overwrites d_out.
__global__ __launch_bounds__(192) void combine_kernel(
    const float* __restrict__ ybuf, const int* __restrict__ slot_of,
    const float* __restrict__ topk_w, float* __restrict__ out)
{
    int t = blockIdx.x;
    int q = threadIdx.x;
    int s0 = slot_of[2*t], s1 = slot_of[2*t+1];
    float w0 = topk_w[2*t], w1 = topk_w[2*t+1];
    f32x4 y0 = reinterpret_cast<const f32x4*>(ybuf + (size_t)s0 * DDIM)[q];
    f32x4 y1 = reinterpret_cast<const f32x4*>(ybuf + (size_t)s1 * DDIM)[q];
    f32x4 o;
#pragma unroll
    for (int r = 0; r < 4; r++) o[r] = w0 * y0[r] + w1 * y1[r];
    reinterpret_cast<f32x4*>(out + (size_t)t * DDIM)[q] = o;
}

// ---------------- launch ----------------
extern "C" void kernel_launch(void* const* d_in, const int* in_sizes, int n_in,
                              void* d_out, int out_size, void* d_ws, size_t ws_size,
                              hipStream_t stream)
{
    if (ws_size < WS_NEEDED) return;

    const float* x      = (const float*)d_in[0];
    const float* gate_w = (const float*)d_in[1];
    const float* gbank  = (const float*)d_in[2];
    const float* ubank  = (const float*)d_in[3];
    const float* dbank  = (const float*)d_in[4];
    float* out = (float*)d_out;

    char* ws = (char*)d_ws;
    __bf16* xb   = (__bf16*)(ws + XB_OFF);
    __bf16* Gt   = (__bf16*)(ws + GT_OFF);
    __bf16* Ut   = (__bf16*)(ws + UT_OFF);
    float*  ybuf = (float*)(ws + YB_OFF);
    __bf16* Dt   = (__bf16*)(ws + DT_OFF);
    __bf16* hbuf = (__bf16*)(ws + HB_OFF);
    int*    tki  = (int*)(ws + TKI_OFF);
    float*  tkw  = (float*)(ws + TKW_OFF);
    int*    pt   = (int*)(ws + PT_OFF);
    int*    slot = (int*)(ws + SL_OFF);
    int*    ctrl = (int*)(ws + CTRL_OFF);

    gating_kernel<<<NTOK / 4, 256, 0, stream>>>(x, gate_w, tki, tkw, xb);
    mega_kernel<<<NTTILE + 1, RTHREADS, 0, stream>>>(
        gbank, ubank, dbank, Gt, Ut, Dt, tki, ctrl, pt, slot);

    gateup_kernel<<<MAXMB * (HDIM / 128), 256, 0, stream>>>(xb, Gt, Ut, ctrl, pt, hbuf);
    down_kernel<<<MAXMB * (DDIM / 128), 256, 0, stream>>>(hbuf, Dt, ctrl, ybuf);
    combine_kernel<<<NTOK, 192, 0, stream>>>(ybuf, slot, tkw, out);
}